// Round 1
// baseline (2060.051 us; speedup 1.0000x reference)
//
#include <hip/hip_runtime.h>
#include <hip/hip_bf16.h>
#include <math.h>

#define D    256
#define K3   768
#define BM   16
#define LN_EPS 1e-5f

// ---------------------------------------------------------------------------
// Kernel 1: LayerNorm over every row of G_t -> d_out.
// One wave (64 lanes) per row, 4 rows per 256-thread block.
// Each lane loads float4 (16B) => 64 lanes cover 256 floats. Memory-bound.
// Rows that have a head update get overwritten later by the gate kernel.
// ---------------------------------------------------------------------------
__global__ __launch_bounds__(256) void ln_all_kernel(
    const float* __restrict__ G_t,
    const float* __restrict__ gamma,
    const float* __restrict__ beta,
    float* __restrict__ out,
    int N)
{
    const int wid  = threadIdx.x >> 6;   // wave id 0..3
    const int lane = threadIdx.x & 63;
    const int row  = blockIdx.x * 4 + wid;
    if (row >= N) return;

    const float4 v = reinterpret_cast<const float4*>(G_t + (size_t)row * D)[lane];

    float s  = v.x + v.y + v.z + v.w;
    float sq = v.x * v.x + v.y * v.y + v.z * v.z + v.w * v.w;
    #pragma unroll
    for (int off = 32; off >= 1; off >>= 1) {
        s  += __shfl_xor(s,  off, 64);
        sq += __shfl_xor(sq, off, 64);
    }
    const float mu  = s * (1.0f / D);
    const float var = sq * (1.0f / D) - mu * mu;
    const float inv = rsqrtf(var + LN_EPS);

    const float4 g4 = reinterpret_cast<const float4*>(gamma)[lane];
    const float4 b4 = reinterpret_cast<const float4*>(beta)[lane];

    float4 o;
    o.x = (v.x - mu) * inv * g4.x + b4.x;
    o.y = (v.y - mu) * inv * g4.y + b4.y;
    o.z = (v.z - mu) * inv * g4.z + b4.z;
    o.w = (v.w - mu) * inv * g4.w + b4.w;
    reinterpret_cast<float4*>(out + (size_t)row * D)[lane] = o;
}

// ---------------------------------------------------------------------------
// Kernel 2: fused gate GEMM + sigmoid + gated residual + LayerNorm + scatter.
// Block = 256 threads, handles BM=16 rows of the [M,768] A matrix.
// A-tile (gathered concat [G_t[h] | G_h | q]) staged once in LDS (48 KB).
// Thread j owns output column j; 16 f32 accumulators; W read coalesced
// (stays L2-resident: 786 KB < 4 MiB/XCD).
// Epilogue: u = A[:, j]*sigmoid(acc) + A[:, 256+j] (both already in LDS),
// per-row LN via wave shfl + cross-wave LDS combine, scatter to out[h].
// ---------------------------------------------------------------------------
__global__ __launch_bounds__(256) void gate_kernel(
    const float* __restrict__ G_t,
    const float* __restrict__ G_h,
    const float* __restrict__ qin,
    const int*   __restrict__ hmap,
    const float* __restrict__ Wg,      // [768,256] row-major
    const float* __restrict__ gamma,
    const float* __restrict__ beta,
    float* __restrict__ out,
    int M)
{
    __shared__ float Alds[BM][K3];
    __shared__ float red_s[4][BM];
    __shared__ float red_q[4][BM];

    const int tid = threadIdx.x;
    const int m0  = blockIdx.x * BM;

    // ---- stage A-tile: 16 rows x 768 cols = 3072 float4, 12 per thread ----
    for (int i4 = tid; i4 < BM * (K3 / 4); i4 += 256) {
        const int row = i4 / (K3 / 4);       // 0..15
        const int c   = i4 % (K3 / 4);       // 0..191 (float4 col)
        const int m   = m0 + row;
        float4 v = make_float4(0.f, 0.f, 0.f, 0.f);
        if (m < M) {
            if (c < 64) {
                const int h = hmap[m];
                v = reinterpret_cast<const float4*>(G_t + (size_t)h * D)[c];
            } else if (c < 128) {
                v = reinterpret_cast<const float4*>(G_h + (size_t)m * D)[c - 64];
            } else {
                v = reinterpret_cast<const float4*>(qin + (size_t)m * D)[c - 128];
            }
        }
        reinterpret_cast<float4*>(&Alds[row][0])[c] = v;
    }
    __syncthreads();

    // ---- GEMM: acc[r] = sum_k A[r][k] * W[k][j] ----
    float acc[BM];
    #pragma unroll
    for (int r = 0; r < BM; ++r) acc[r] = 0.f;

    const int j = tid;                        // output column 0..255
    for (int k0 = 0; k0 < K3; k0 += 8) {
        float w[8];
        #pragma unroll
        for (int kk = 0; kk < 8; ++kk) w[kk] = Wg[(size_t)(k0 + kk) * D + j];
        #pragma unroll
        for (int r = 0; r < BM; ++r) {
            const float4* ap = reinterpret_cast<const float4*>(&Alds[r][k0]);
            const float4 a0 = ap[0];
            const float4 a1 = ap[1];
            acc[r] = fmaf(a0.x, w[0], acc[r]);
            acc[r] = fmaf(a0.y, w[1], acc[r]);
            acc[r] = fmaf(a0.z, w[2], acc[r]);
            acc[r] = fmaf(a0.w, w[3], acc[r]);
            acc[r] = fmaf(a1.x, w[4], acc[r]);
            acc[r] = fmaf(a1.y, w[5], acc[r]);
            acc[r] = fmaf(a1.z, w[6], acc[r]);
            acc[r] = fmaf(a1.w, w[7], acc[r]);
        }
    }

    // ---- epilogue: sigmoid gate + residual ----
    const int lane = tid & 63;
    const int wid  = tid >> 6;
    float u[BM];
    #pragma unroll
    for (int r = 0; r < BM; ++r) {
        const float g = 1.0f / (1.0f + __expf(-acc[r]));
        u[r] = Alds[r][j] * g + Alds[r][D + j];   // G_t_has_h * g + G_h
    }

    // ---- per-row reductions for LN (sum, sumsq over 256 threads) ----
    #pragma unroll
    for (int r = 0; r < BM; ++r) {
        float s  = u[r];
        float sq = u[r] * u[r];
        #pragma unroll
        for (int off = 32; off >= 1; off >>= 1) {
            s  += __shfl_xor(s,  off, 64);
            sq += __shfl_xor(sq, off, 64);
        }
        if (lane == 0) { red_s[wid][r] = s; red_q[wid][r] = sq; }
    }
    __syncthreads();

    const float ga = gamma[j];
    const float be = beta[j];
    #pragma unroll
    for (int r = 0; r < BM; ++r) {
        const int m = m0 + r;
        if (m >= M) break;
        const float s   = red_s[0][r] + red_s[1][r] + red_s[2][r] + red_s[3][r];
        const float sq  = red_q[0][r] + red_q[1][r] + red_q[2][r] + red_q[3][r];
        const float mu  = s * (1.0f / D);
        const float var = sq * (1.0f / D) - mu * mu;
        const float inv = rsqrtf(var + LN_EPS);
        const int h = hmap[m];
        out[(size_t)h * D + j] = (u[r] - mu) * inv * ga + be;
    }
}

// ---------------------------------------------------------------------------
extern "C" void kernel_launch(void* const* d_in, const int* in_sizes, int n_in,
                              void* d_out, int out_size, void* d_ws, size_t ws_size,
                              hipStream_t stream)
{
    (void)n_in; (void)d_ws; (void)ws_size; (void)out_size;

    const float* G_t   = (const float*)d_in[0];
    const float* G_h   = (const float*)d_in[1];
    const float* qin   = (const float*)d_in[2];
    const int*   hmap  = (const int*)  d_in[3];   // int32 (JAX x64 disabled)
    const float* Wg    = (const float*)d_in[4];
    const float* gamma = (const float*)d_in[5];
    const float* beta  = (const float*)d_in[6];
    float* out = (float*)d_out;

    const int N = in_sizes[0] / D;
    const int M = in_sizes[1] / D;

    // 1) LN of every G_t row (updated rows get stale values here...)
    ln_all_kernel<<<(N + 3) / 4, 256, 0, stream>>>(G_t, gamma, beta, out, N);
    // 2) ...then the gate kernel overwrites the M updated rows (stream order).
    gate_kernel<<<(M + BM - 1) / BM, 256, 0, stream>>>(G_t, G_h, qin, hmap, Wg,
                                                       gamma, beta, out, M);
}